// Round 1
// baseline (795.409 us; speedup 1.0000x reference)
//
#include <hip/hip_runtime.h>
#include <math.h>

#define NK 6
#define NB 8
#define NT 12
#define D 256      // DIM == HALF == 256
#define NG 8       // offset groups == sampling points
#define NHD 8      // num heads
#define HW 256     // HBEV == WBEV
#define NQ (NK*NB*NT)   // 576 queries
#define NR (NQ*NG)      // 4608 sampled rows
#define TR 16           // rows per K2 tile (4608 % 16 == 0)

// workspace layout (float offsets)
#define WS_CONQ 0
#define WS_POSQ (WS_CONQ + NQ*D)
#define WS_SAMP (WS_POSQ + NQ*D)
#define WS_KSE  (WS_SAMP + NR*D)
#define WS_CONK (WS_KSE  + NR*D)
#define WS_VMAT (WS_CONK + NR*D)
#define WS_POSK (WS_VMAT + NR*D)
#define WS_TOTAL (WS_POSK + NR*D)   // 6,193,152 floats = ~24.8 MB

// ---------------------------------------------------------------------------
// K1: per-query front end: con_q GEMV, offset MLP, bilinear gather, sine
//     embeds, pos_q MLP.  Writes conq/posq/samp/kse to workspace.
// ---------------------------------------------------------------------------
__global__ __launch_bounds__(256)
void k1_front(const float* __restrict__ dec_embed,
              const float* __restrict__ bev_feat,
              const float* __restrict__ query_scale,
              const float* __restrict__ ref_points,
              const float* __restrict__ Wq,     const float* __restrict__ bq,
              const float* __restrict__ pq_W1,  const float* __restrict__ pq_b1,
              const float* __restrict__ pq_W2,  const float* __restrict__ pq_b2,
              const float* __restrict__ off_W1, const float* __restrict__ off_b1,
              const float* __restrict__ off_W2, const float* __restrict__ off_b2,
              float* __restrict__ ws)
{
    __shared__ float de[D];
    __shared__ float conq[D];
    __shared__ float qse[D];
    __shared__ float tmp1[D];
    __shared__ float h1[NG][64];
    __shared__ float gxy[NG][2];

    const int tid = threadIdx.x;
    const int q   = blockIdx.x;
    const int bb  = (q / NT) % NB;

    const float NORM = 0.01953125f;          // 2/102.4
    const float TWO_PI = 6.28318530717958647692f;
    const float L2_40_OVER_64 = 5.32192809488736234787f / 64.0f;

    de[tid] = dec_embed[(size_t)q * D + tid];
    __syncthreads();

    // con_q = de @ Wq + bq
    {
        float acc = bq[tid];
        #pragma unroll 8
        for (int i = 0; i < D; ++i) acc += de[i] * Wq[i * D + tid];
        conq[tid] = acc;
        ws[WS_CONQ + (size_t)q * D + tid] = acc;
    }
    __syncthreads();

    // offset MLP layer 1 (per group, 32 -> 64, exact GELU)
    for (int idx = tid; idx < NG * 64; idx += 256) {
        int g = idx >> 6, j = idx & 63;
        float acc = off_b1[j];
        #pragma unroll 8
        for (int i = 0; i < 32; ++i) acc += conq[g * 32 + i] * off_W1[i * 64 + j];
        h1[g][j] = 0.5f * acc * (1.0f + erff(acc * 0.70710678118654752440f));
    }
    __syncthreads();

    // offset MLP layer 2 (64 -> 2), tanh*4, add ref point, normalize
    if (tid < NG * 2) {
        int g = tid >> 1, c = tid & 1;
        float acc = off_b2[c];
        #pragma unroll 8
        for (int j = 0; j < 64; ++j) acc += h1[g][j] * off_W2[j * 2 + c];
        float off = tanhf(acc) * 4.0f;
        float rp  = ref_points[(size_t)q * 2 + c];
        gxy[g][c] = (rp + off) * NORM;
    }
    // qse: sine embed of ref_scaled (independent of gxy; same barrier covers both)
    {
        float rx = ref_points[(size_t)q * 2 + 0] * NORM;
        float ry = ref_points[(size_t)q * 2 + 1] * NORM;
        int j = tid;
        float pos = (j < 128) ? ry : rx;
        int m = (j & 127) >> 1;
        float freq = TWO_PI / exp2f((float)m * L2_40_OVER_64);
        float e = pos * freq;
        qse[j] = (j & 1) ? cosf(e) : sinf(e);
    }
    __syncthreads();

    // bilinear sampling (zeros pad, align_corners=False) -> ws samp rows
    {
        const float* ch = bev_feat + ((size_t)bb * D + tid) * HW * HW;
        #pragma unroll
        for (int g = 0; g < NG; ++g) {
            float gx = gxy[g][0], gy = gxy[g][1];
            float ix = ((gx + 1.0f) * HW - 1.0f) * 0.5f;
            float iy = ((gy + 1.0f) * HW - 1.0f) * 0.5f;
            float fx0 = floorf(ix), fy0 = floorf(iy);
            float wx = ix - fx0, wy = iy - fy0;
            int x0 = (int)fx0, y0 = (int)fy0;
            bool xin0 = (x0 >= 0) && (x0 < HW);
            bool xin1 = (x0 + 1 >= 0) && (x0 + 1 < HW);
            bool yin0 = (y0 >= 0) && (y0 < HW);
            bool yin1 = (y0 + 1 >= 0) && (y0 + 1 < HW);
            float v00 = 0.f, v01 = 0.f, v10 = 0.f, v11 = 0.f;
            if (yin0) {
                if (xin0) v00 = ch[y0 * HW + x0];
                if (xin1) v01 = ch[y0 * HW + x0 + 1];
            }
            if (yin1) {
                if (xin0) v10 = ch[(y0 + 1) * HW + x0];
                if (xin1) v11 = ch[(y0 + 1) * HW + x0 + 1];
            }
            float val = v00 * (1.f - wx) * (1.f - wy) + v01 * wx * (1.f - wy)
                      + v10 * (1.f - wx) * wy        + v11 * wx * wy;
            ws[WS_SAMP + (size_t)(q * NG + g) * D + tid] = val;
        }
        // kse rows
        int m = (tid & 127) >> 1;
        float freq = TWO_PI / exp2f((float)m * L2_40_OVER_64);
        #pragma unroll
        for (int g = 0; g < NG; ++g) {
            float pos = (tid < 128) ? gxy[g][1] : gxy[g][0];
            float e = pos * freq;
            ws[WS_KSE + (size_t)(q * NG + g) * D + tid] = (tid & 1) ? cosf(e) : sinf(e);
        }
    }

    // pos_q layer 1 (qse already synced)
    {
        float a1 = pq_b1[tid];
        #pragma unroll 8
        for (int i = 0; i < D; ++i) a1 += qse[i] * pq_W1[i * D + tid];
        tmp1[tid] = fmaxf(a1, 0.f);
    }
    __syncthreads();
    // pos_q layer 2, * query_scale
    {
        float a2 = pq_b2[tid];
        #pragma unroll 8
        for (int i = 0; i < D; ++i) a2 += tmp1[i] * pq_W2[i * D + tid];
        ws[WS_POSQ + (size_t)q * D + tid] = a2 * query_scale[(size_t)q * D + tid];
    }
}

// ---------------------------------------------------------------------------
// K2: row-batched GEMMs over the 4608 sampled rows.
//   blocks [0, NR/TR):       conk = samp @ Wk ; vmat = samp @ Wv
//   blocks [NR/TR, 2*NR/TR): posk = relu(kse @ pk_W1 + b1) @ pk_W2 + b2
// 16-row LDS tile; weights streamed once per 16 rows (vs once per query).
// ---------------------------------------------------------------------------
__global__ __launch_bounds__(256)
void k2_gemms(const float* __restrict__ Wk, const float* __restrict__ Wv,
              const float* __restrict__ pk_W1, const float* __restrict__ pk_b1,
              const float* __restrict__ pk_W2, const float* __restrict__ pk_b2,
              float* __restrict__ ws)
{
    __shared__ float sIn[TR][D];
    __shared__ float sH[TR][D];
    const int tid = threadIdx.x;
    const int b = blockIdx.x;

    if (b < NR / TR) {
        // ---- job A: conk / vmat ----
        const int r0 = b * TR;
        const float* samp = ws + WS_SAMP;
        for (int idx = tid; idx < TR * D; idx += 256)
            sIn[idx >> 8][idx & 255] = samp[(size_t)(r0 + (idx >> 8)) * D + (idx & 255)];
        __syncthreads();

        float accK[TR], accV[TR];
        #pragma unroll
        for (int r = 0; r < TR; ++r) { accK[r] = 0.f; accV[r] = 0.f; }

        #pragma unroll 2
        for (int i = 0; i < D; i += 4) {
            float wk0 = Wk[(i + 0) * D + tid], wk1 = Wk[(i + 1) * D + tid];
            float wk2 = Wk[(i + 2) * D + tid], wk3 = Wk[(i + 3) * D + tid];
            float wv0 = Wv[(i + 0) * D + tid], wv1 = Wv[(i + 1) * D + tid];
            float wv2 = Wv[(i + 2) * D + tid], wv3 = Wv[(i + 3) * D + tid];
            #pragma unroll
            for (int r = 0; r < TR; ++r) {
                float4 s = *(const float4*)&sIn[r][i];
                accK[r] += s.x * wk0 + s.y * wk1 + s.z * wk2 + s.w * wk3;
                accV[r] += s.x * wv0 + s.y * wv1 + s.z * wv2 + s.w * wv3;
            }
        }
        float* conk = ws + WS_CONK;
        float* vmat = ws + WS_VMAT;
        #pragma unroll
        for (int r = 0; r < TR; ++r) {
            conk[(size_t)(r0 + r) * D + tid] = accK[r];
            vmat[(size_t)(r0 + r) * D + tid] = accV[r];
        }
    } else {
        // ---- job B: posk two-layer MLP ----
        const int r0 = (b - NR / TR) * TR;
        const float* kse = ws + WS_KSE;
        for (int idx = tid; idx < TR * D; idx += 256)
            sIn[idx >> 8][idx & 255] = kse[(size_t)(r0 + (idx >> 8)) * D + (idx & 255)];
        __syncthreads();

        float acc[TR];
        float b1 = pk_b1[tid];
        #pragma unroll
        for (int r = 0; r < TR; ++r) acc[r] = b1;

        #pragma unroll 2
        for (int i = 0; i < D; i += 4) {
            float w0 = pk_W1[(i + 0) * D + tid], w1 = pk_W1[(i + 1) * D + tid];
            float w2 = pk_W1[(i + 2) * D + tid], w3 = pk_W1[(i + 3) * D + tid];
            #pragma unroll
            for (int r = 0; r < TR; ++r) {
                float4 s = *(const float4*)&sIn[r][i];
                acc[r] += s.x * w0 + s.y * w1 + s.z * w2 + s.w * w3;
            }
        }
        #pragma unroll
        for (int r = 0; r < TR; ++r) sH[r][tid] = fmaxf(acc[r], 0.f);
        __syncthreads();

        float b2 = pk_b2[tid];
        #pragma unroll
        for (int r = 0; r < TR; ++r) acc[r] = b2;
        #pragma unroll 2
        for (int i = 0; i < D; i += 4) {
            float w0 = pk_W2[(i + 0) * D + tid], w1 = pk_W2[(i + 1) * D + tid];
            float w2 = pk_W2[(i + 2) * D + tid], w3 = pk_W2[(i + 3) * D + tid];
            #pragma unroll
            for (int r = 0; r < TR; ++r) {
                float4 s = *(const float4*)&sH[r][i];
                acc[r] += s.x * w0 + s.y * w1 + s.z * w2 + s.w * w3;
            }
        }
        float* posk = ws + WS_POSK;
        #pragma unroll
        for (int r = 0; r < TR; ++r)
            posk[(size_t)(r0 + r) * D + tid] = acc[r];
    }
}

// ---------------------------------------------------------------------------
// K3: attention (sim/softmax/PV) + output projection + residual
// ---------------------------------------------------------------------------
__global__ __launch_bounds__(256)
void k3_attn(const float* __restrict__ dec_embed,
             const float* __restrict__ out_W, const float* __restrict__ out_b,
             const float* __restrict__ ws,
             float* __restrict__ out)
{
    __shared__ float cq[D];
    __shared__ float pq[D];
    __shared__ float oatt[D];
    __shared__ float ck[NG][D];
    __shared__ float pk[NG][D];
    __shared__ float vv[NG][D];
    __shared__ float sim[NHD][NG];

    const int tid = threadIdx.x;
    const int q = blockIdx.x;

    cq[tid] = ws[WS_CONQ + (size_t)q * D + tid];
    pq[tid] = ws[WS_POSQ + (size_t)q * D + tid];
    #pragma unroll
    for (int g = 0; g < NG; ++g) {
        ck[g][tid] = ws[WS_CONK + (size_t)(q * NG + g) * D + tid];
        pk[g][tid] = ws[WS_POSK + (size_t)(q * NG + g) * D + tid];
        vv[g][tid] = ws[WS_VMAT + (size_t)(q * NG + g) * D + tid];
    }
    __syncthreads();

    if (tid < NHD * NG) {
        int h = tid >> 3, g = tid & 7;
        float s = 0.f;
        #pragma unroll 8
        for (int d = 0; d < 32; ++d) {
            s += cq[h * 32 + d] * ck[g][h * 32 + d];
            s += pq[h * 32 + d] * pk[g][h * 32 + d];
        }
        sim[h][g] = s * 0.125f;   // SCALE = 64^-0.5
    }
    __syncthreads();

    if (tid < NHD) {
        int h = tid;
        float mx = sim[h][0];
        for (int g = 1; g < NG; ++g) mx = fmaxf(mx, sim[h][g]);
        float ex[NG], sum = 0.f;
        #pragma unroll
        for (int g = 0; g < NG; ++g) { ex[g] = expf(sim[h][g] - mx); sum += ex[g]; }
        float inv = 1.0f / sum;
        #pragma unroll
        for (int g = 0; g < NG; ++g) sim[h][g] = ex[g] * inv;
    }
    __syncthreads();

    {
        int h = tid >> 5, d = tid & 31;
        float o = 0.f;
        #pragma unroll
        for (int g = 0; g < NG; ++g) o += sim[h][g] * vv[g][h * 32 + d];
        oatt[tid] = o;
    }
    __syncthreads();

    {
        float acc = out_b[tid];
        #pragma unroll 8
        for (int i = 0; i < D; ++i) acc += oatt[i] * out_W[i * D + tid];
        out[(size_t)q * D + tid] = acc + dec_embed[(size_t)q * D + tid];
    }
}

// ---------------------------------------------------------------------------
// Fallback: previous proven monolithic kernel (used if ws too small)
// ---------------------------------------------------------------------------
__global__ __launch_bounds__(256)
void dca_kernel(const float* __restrict__ dec_embed,
                const float* __restrict__ bev_feat,
                const float* __restrict__ query_scale,
                const float* __restrict__ ref_points,
                const float* __restrict__ Wq,     const float* __restrict__ bq,
                const float* __restrict__ Wk,     const float* __restrict__ Wv,
                const float* __restrict__ pq_W1,  const float* __restrict__ pq_b1,
                const float* __restrict__ pq_W2,  const float* __restrict__ pq_b2,
                const float* __restrict__ pk_W1,  const float* __restrict__ pk_b1,
                const float* __restrict__ pk_W2,  const float* __restrict__ pk_b2,
                const float* __restrict__ off_W1, const float* __restrict__ off_b1,
                const float* __restrict__ off_W2, const float* __restrict__ off_b2,
                const float* __restrict__ out_W,  const float* __restrict__ out_b,
                float* __restrict__ out)
{
    __shared__ float de[D];
    __shared__ float conq[D];
    __shared__ float qse[D];
    __shared__ float tmp1[D];
    __shared__ float posq[D];
    __shared__ float oatt[D];
    __shared__ float h1[NG][64];
    __shared__ float gxy[NG][2];
    __shared__ float sim[NHD][NG];
    __shared__ float bufA[NG][D];
    __shared__ float bufB[NG][D];
    __shared__ float conk[NG][D];
    __shared__ float vmat[NG][D];

    const int tid = threadIdx.x;
    const int q   = blockIdx.x;
    const int bb  = (q / NT) % NB;

    const float NORM = 0.01953125f;
    const float TWO_PI = 6.28318530717958647692f;
    const float L2_40_OVER_64 = 5.32192809488736234787f / 64.0f;

    de[tid] = dec_embed[(size_t)q * D + tid];
    __syncthreads();
    {
        float acc = bq[tid];
        #pragma unroll 8
        for (int i = 0; i < D; ++i) acc += de[i] * Wq[i * D + tid];
        conq[tid] = acc;
    }
    __syncthreads();
    for (int idx = tid; idx < NG * 64; idx += 256) {
        int g = idx >> 6, j = idx & 63;
        float acc = off_b1[j];
        #pragma unroll 8
        for (int i = 0; i < 32; ++i) acc += conq[g * 32 + i] * off_W1[i * 64 + j];
        h1[g][j] = 0.5f * acc * (1.0f + erff(acc * 0.70710678118654752440f));
    }
    __syncthreads();
    if (tid < NG * 2) {
        int g = tid >> 1, c = tid & 1;
        float acc = off_b2[c];
        #pragma unroll 8
        for (int j = 0; j < 64; ++j) acc += h1[g][j] * off_W2[j * 2 + c];
        float off = tanhf(acc) * 4.0f;
        float rp  = ref_points[(size_t)q * 2 + c];
        gxy[g][c] = (rp + off) * NORM;
    }
    __syncthreads();
    {
        const float* bevb = bev_feat + (size_t)bb * D * HW * HW;
        const int c = tid;
        const float* ch = bevb + (size_t)c * HW * HW;
        #pragma unroll
        for (int g = 0; g < NG; ++g) {
            float gx = gxy[g][0], gy = gxy[g][1];
            float ix = ((gx + 1.0f) * HW - 1.0f) * 0.5f;
            float iy = ((gy + 1.0f) * HW - 1.0f) * 0.5f;
            float fx0 = floorf(ix), fy0 = floorf(iy);
            float wx = ix - fx0, wy = iy - fy0;
            int x0 = (int)fx0, y0 = (int)fy0;
            bool xin0 = (x0 >= 0) && (x0 < HW);
            bool xin1 = (x0 + 1 >= 0) && (x0 + 1 < HW);
            bool yin0 = (y0 >= 0) && (y0 < HW);
            bool yin1 = (y0 + 1 >= 0) && (y0 + 1 < HW);
            float v00 = 0.f, v01 = 0.f, v10 = 0.f, v11 = 0.f;
            if (yin0) {
                if (xin0) v00 = ch[y0 * HW + x0];
                if (xin1) v01 = ch[y0 * HW + x0 + 1];
            }
            if (yin1) {
                if (xin0) v10 = ch[(y0 + 1) * HW + x0];
                if (xin1) v11 = ch[(y0 + 1) * HW + x0 + 1];
            }
            bufA[g][c] = v00 * (1.f - wx) * (1.f - wy) + v01 * wx * (1.f - wy)
                       + v10 * (1.f - wx) * wy        + v11 * wx * wy;
        }
        {
            float rx = ref_points[(size_t)q * 2 + 0] * NORM;
            float ry = ref_points[(size_t)q * 2 + 1] * NORM;
            int j = tid;
            float pos = (j < 128) ? ry : rx;
            int m = (j & 127) >> 1;
            float freq = TWO_PI / exp2f((float)m * L2_40_OVER_64);
            float e = pos * freq;
            qse[j] = (j & 1) ? cosf(e) : sinf(e);
        }
        #pragma unroll
        for (int g = 0; g < NG; ++g) {
            int j = tid;
            float pos = (j < 128) ? gxy[g][1] : gxy[g][0];
            int m = (j & 127) >> 1;
            float freq = TWO_PI / exp2f((float)m * L2_40_OVER_64);
            float e = pos * freq;
            bufB[g][j] = (j & 1) ? cosf(e) : sinf(e);
        }
    }
    __syncthreads();
    {
        float accK[NG], accV[NG];
        #pragma unroll
        for (int g = 0; g < NG; ++g) { accK[g] = 0.f; accV[g] = 0.f; }
        #pragma unroll 4
        for (int i = 0; i < D; ++i) {
            float wk = Wk[i * D + tid];
            float wv = Wv[i * D + tid];
            #pragma unroll
            for (int g = 0; g < NG; ++g) {
                float s = bufA[g][i];
                accK[g] += s * wk;
                accV[g] += s * wv;
            }
        }
        #pragma unroll
        for (int g = 0; g < NG; ++g) { conk[g][tid] = accK[g]; vmat[g][tid] = accV[g]; }
    }
    __syncthreads();
    {
        float acc[NG + 1];
        float biask = pk_b1[tid];
        #pragma unroll
        for (int g = 0; g < NG; ++g) acc[g] = biask;
        acc[NG] = pq_b1[tid];
        #pragma unroll 4
        for (int i = 0; i < D; ++i) {
            float wk1 = pk_W1[i * D + tid];
            float wq1 = pq_W1[i * D + tid];
            #pragma unroll
            for (int g = 0; g < NG; ++g) acc[g] += bufB[g][i] * wk1;
            acc[NG] += qse[i] * wq1;
        }
        #pragma unroll
        for (int g = 0; g < NG; ++g) bufA[g][tid] = fmaxf(acc[g], 0.f);
        tmp1[tid] = fmaxf(acc[NG], 0.f);
    }
    __syncthreads();
    {
        float acc[NG + 1];
        float biask = pk_b2[tid];
        #pragma unroll
        for (int g = 0; g < NG; ++g) acc[g] = biask;
        acc[NG] = pq_b2[tid];
        #pragma unroll 4
        for (int i = 0; i < D; ++i) {
            float wk2 = pk_W2[i * D + tid];
            float wq2 = pq_W2[i * D + tid];
            #pragma unroll
            for (int g = 0; g < NG; ++g) acc[g] += bufA[g][i] * wk2;
            acc[NG] += tmp1[i] * wq2;
        }
        #pragma unroll
        for (int g = 0; g < NG; ++g) bufB[g][tid] = acc[g];
        posq[tid] = acc[NG] * query_scale[(size_t)q * D + tid];
    }
    __syncthreads();
    if (tid < NHD * NG) {
        int h = tid >> 3, g = tid & 7;
        float s = 0.f;
        #pragma unroll 8
        for (int d = 0; d < 32; ++d) {
            s += conq[h * 32 + d] * conk[g][h * 32 + d];
            s += posq[h * 32 + d] * bufB[g][h * 32 + d];
        }
        sim[h][g] = s * 0.125f;
    }
    __syncthreads();
    if (tid < NHD) {
        int h = tid;
        float mx = sim[h][0];
        for (int g = 1; g < NG; ++g) mx = fmaxf(mx, sim[h][g]);
        float ex[NG], sum = 0.f;
        #pragma unroll
        for (int g = 0; g < NG; ++g) { ex[g] = expf(sim[h][g] - mx); sum += ex[g]; }
        float inv = 1.0f / sum;
        #pragma unroll
        for (int g = 0; g < NG; ++g) sim[h][g] = ex[g] * inv;
    }
    __syncthreads();
    {
        int h = tid >> 5, d = tid & 31;
        float o = 0.f;
        #pragma unroll
        for (int g = 0; g < NG; ++g) o += sim[h][g] * vmat[g][h * 32 + d];
        oatt[tid] = o;
    }
    __syncthreads();
    {
        float acc = out_b[tid];
        #pragma unroll 8
        for (int i = 0; i < D; ++i) acc += oatt[i] * out_W[i * D + tid];
        out[(size_t)q * D + tid] = acc + de[tid];
    }
}

extern "C" void kernel_launch(void* const* d_in, const int* in_sizes, int n_in,
                              void* d_out, int out_size, void* d_ws, size_t ws_size,
                              hipStream_t stream) {
    const float* dec_embed   = (const float*)d_in[0];
    const float* bev_feat    = (const float*)d_in[1];
    const float* query_scale = (const float*)d_in[2];
    const float* ref_points  = (const float*)d_in[3];
    const float* Wq     = (const float*)d_in[4];
    const float* bq     = (const float*)d_in[5];
    const float* Wk     = (const float*)d_in[6];
    const float* Wv     = (const float*)d_in[7];
    const float* pq_W1  = (const float*)d_in[8];
    const float* pq_b1  = (const float*)d_in[9];
    const float* pq_W2  = (const float*)d_in[10];
    const float* pq_b2  = (const float*)d_in[11];
    const float* pk_W1  = (const float*)d_in[12];
    const float* pk_b1  = (const float*)d_in[13];
    const float* pk_W2  = (const float*)d_in[14];
    const float* pk_b2  = (const float*)d_in[15];
    const float* off_W1 = (const float*)d_in[16];
    const float* off_b1 = (const float*)d_in[17];
    const float* off_W2 = (const float*)d_in[18];
    const float* off_b2 = (const float*)d_in[19];
    const float* out_W  = (const float*)d_in[20];
    const float* out_b  = (const float*)d_in[21];
    float* out = (float*)d_out;
    float* ws = (float*)d_ws;

    if (ws_size >= (size_t)WS_TOTAL * sizeof(float)) {
        k1_front<<<NQ, 256, 0, stream>>>(dec_embed, bev_feat, query_scale, ref_points,
                                         Wq, bq, pq_W1, pq_b1, pq_W2, pq_b2,
                                         off_W1, off_b1, off_W2, off_b2, ws);
        k2_gemms<<<2 * (NR / TR), 256, 0, stream>>>(Wk, Wv, pk_W1, pk_b1, pk_W2, pk_b2, ws);
        k3_attn<<<NQ, 256, 0, stream>>>(dec_embed, out_W, out_b, ws, out);
    } else {
        dca_kernel<<<NQ, 256, 0, stream>>>(dec_embed, bev_feat, query_scale, ref_points,
                                           Wq, bq, Wk, Wv,
                                           pq_W1, pq_b1, pq_W2, pq_b2,
                                           pk_W1, pk_b1, pk_W2, pk_b2,
                                           off_W1, off_b1, off_W2, off_b2,
                                           out_W, out_b, out);
    }
}

// Round 2
// 737.195 us; speedup vs baseline: 1.0790x; 1.0790x over previous
//
#include <hip/hip_runtime.h>
#include <math.h>

#define NK 6
#define NB 8
#define NT 12
#define D 256      // DIM == HALF == 256
#define NG 8       // offset groups == sampling points
#define NHD 8      // num heads
#define HW 256     // HBEV == WBEV
#define NQ (NK*NB*NT)   // 576 queries

// Monolithic per-query kernel. All LDS operand reads in GEMV i-loops are
// float4 (ds_read_b128): the scalar-read version was LDS-issue-bound
// (8-9 ds_read_b32 per i vs 16-18 FMA).
__global__ __launch_bounds__(256)
void dca_kernel(const float* __restrict__ dec_embed,
                const float* __restrict__ bev_feat,
                const float* __restrict__ query_scale,
                const float* __restrict__ ref_points,
                const float* __restrict__ Wq,     const float* __restrict__ bq,
                const float* __restrict__ Wk,     const float* __restrict__ Wv,
                const float* __restrict__ pq_W1,  const float* __restrict__ pq_b1,
                const float* __restrict__ pq_W2,  const float* __restrict__ pq_b2,
                const float* __restrict__ pk_W1,  const float* __restrict__ pk_b1,
                const float* __restrict__ pk_W2,  const float* __restrict__ pk_b2,
                const float* __restrict__ off_W1, const float* __restrict__ off_b1,
                const float* __restrict__ off_W2, const float* __restrict__ off_b2,
                const float* __restrict__ out_W,  const float* __restrict__ out_b,
                float* __restrict__ out)
{
    __shared__ float de[D];
    __shared__ float conq[D];
    __shared__ float qse[D];
    __shared__ float tmp1[D];
    __shared__ float posq[D];
    __shared__ float oatt[D];
    __shared__ float h1[NG][64];
    __shared__ float gxy[NG][2];
    __shared__ float sim[NHD][NG];
    // aliased buffers: bufA = samp (st.5-6) then tmpk (st.6-7)
    //                  bufB = kse  (st.5-6) then posk (st.7-10)
    __shared__ float bufA[NG][D];
    __shared__ float bufB[NG][D];
    __shared__ float conk[NG][D];
    __shared__ float vmat[NG][D];

    const int tid = threadIdx.x;
    const int q   = blockIdx.x;              // flattened (k,b,t)
    const int bb  = (q / NT) % NB;           // batch index

    const float NORM = 0.01953125f;          // 2/102.4
    const float TWO_PI = 6.28318530717958647692f;
    const float L2_40_OVER_64 = 5.32192809488736234787f / 64.0f;  // log2(40)/64

    // ---- stage 1: load dec_embed row ----
    de[tid] = dec_embed[(size_t)q * D + tid];
    __syncthreads();

    // ---- stage 2: con_q = de @ Wq + bq (float4 LDS reads) ----
    {
        float acc = bq[tid];
        #pragma unroll 4
        for (int i = 0; i < D; i += 4) {
            float4 d4 = *(const float4*)&de[i];
            acc += d4.x * Wq[(i + 0) * D + tid];
            acc += d4.y * Wq[(i + 1) * D + tid];
            acc += d4.z * Wq[(i + 2) * D + tid];
            acc += d4.w * Wq[(i + 3) * D + tid];
        }
        conq[tid] = acc;
    }
    __syncthreads();

    // ---- stage 3: offset MLP layer 1 (per group, 32 -> 64, exact GELU) ----
    for (int idx = tid; idx < NG * 64; idx += 256) {
        int g = idx >> 6, j = idx & 63;
        float acc = off_b1[j];
        #pragma unroll
        for (int i = 0; i < 32; i += 4) {
            float4 c4 = *(const float4*)&conq[g * 32 + i];
            acc += c4.x * off_W1[(i + 0) * 64 + j];
            acc += c4.y * off_W1[(i + 1) * 64 + j];
            acc += c4.z * off_W1[(i + 2) * 64 + j];
            acc += c4.w * off_W1[(i + 3) * 64 + j];
        }
        h1[g][j] = 0.5f * acc * (1.0f + erff(acc * 0.70710678118654752440f));
    }
    __syncthreads();

    // ---- stage 4: offset MLP layer 2 (64 -> 2), tanh*4, add ref, normalize ----
    if (tid < NG * 2) {
        int g = tid >> 1, c = tid & 1;
        float acc = off_b2[c];
        #pragma unroll
        for (int j = 0; j < 64; j += 4) {
            float4 hh = *(const float4*)&h1[g][j];
            acc += hh.x * off_W2[(j + 0) * 2 + c];
            acc += hh.y * off_W2[(j + 1) * 2 + c];
            acc += hh.z * off_W2[(j + 2) * 2 + c];
            acc += hh.w * off_W2[(j + 3) * 2 + c];
        }
        float off = tanhf(acc) * 4.0f;
        float rp  = ref_points[(size_t)q * 2 + c];
        gxy[g][c] = (rp + off) * NORM;
    }
    __syncthreads();

    // ---- stage 5: bilinear sampling (zeros pad) + sine embeds ----
    {
        const float* ch = bev_feat + ((size_t)bb * D + tid) * HW * HW;
        #pragma unroll
        for (int g = 0; g < NG; ++g) {
            float gx = gxy[g][0], gy = gxy[g][1];
            float ix = ((gx + 1.0f) * HW - 1.0f) * 0.5f;
            float iy = ((gy + 1.0f) * HW - 1.0f) * 0.5f;
            float fx0 = floorf(ix), fy0 = floorf(iy);
            float wx = ix - fx0, wy = iy - fy0;
            int x0 = (int)fx0, y0 = (int)fy0;
            bool xin0 = (x0 >= 0) && (x0 < HW);
            bool xin1 = (x0 + 1 >= 0) && (x0 + 1 < HW);
            bool yin0 = (y0 >= 0) && (y0 < HW);
            bool yin1 = (y0 + 1 >= 0) && (y0 + 1 < HW);
            float v00 = 0.f, v01 = 0.f, v10 = 0.f, v11 = 0.f;
            if (yin0) {
                if (xin0) v00 = ch[y0 * HW + x0];
                if (xin1) v01 = ch[y0 * HW + x0 + 1];
            }
            if (yin1) {
                if (xin0) v10 = ch[(y0 + 1) * HW + x0];
                if (xin1) v11 = ch[(y0 + 1) * HW + x0 + 1];
            }
            bufA[g][tid] = v00 * (1.f - wx) * (1.f - wy) + v01 * wx * (1.f - wy)
                         + v10 * (1.f - wx) * wy        + v11 * wx * wy;   // samp
        }
        // qse: sine embed of ref_scaled.  [0:128) from y, [128:256) from x
        {
            float rx = ref_points[(size_t)q * 2 + 0] * NORM;
            float ry = ref_points[(size_t)q * 2 + 1] * NORM;
            int j = tid;
            float pos = (j < 128) ? ry : rx;
            int m = (j & 127) >> 1;
            float freq = TWO_PI / exp2f((float)m * L2_40_OVER_64);
            float e = pos * freq;
            qse[j] = (j & 1) ? cosf(e) : sinf(e);
        }
        // kse per group
        {
            int m = (tid & 127) >> 1;
            float freq = TWO_PI / exp2f((float)m * L2_40_OVER_64);
            #pragma unroll
            for (int g = 0; g < NG; ++g) {
                float pos = (tid < 128) ? gxy[g][1] : gxy[g][0];
                float e = pos * freq;
                bufB[g][tid] = (tid & 1) ? cosf(e) : sinf(e);   // kse
            }
        }
    }
    __syncthreads();

    // ---- stage 6a: con_k = samp @ Wk, v = samp @ Wv (float4 LDS reads) ----
    {
        float accK[NG], accV[NG];
        #pragma unroll
        for (int g = 0; g < NG; ++g) { accK[g] = 0.f; accV[g] = 0.f; }
        #pragma unroll 2
        for (int i = 0; i < D; i += 4) {
            float wk0 = Wk[(i + 0) * D + tid], wk1 = Wk[(i + 1) * D + tid];
            float wk2 = Wk[(i + 2) * D + tid], wk3 = Wk[(i + 3) * D + tid];
            float wv0 = Wv[(i + 0) * D + tid], wv1 = Wv[(i + 1) * D + tid];
            float wv2 = Wv[(i + 2) * D + tid], wv3 = Wv[(i + 3) * D + tid];
            #pragma unroll
            for (int g = 0; g < NG; ++g) {
                float4 s = *(const float4*)&bufA[g][i];
                accK[g] += s.x * wk0 + s.y * wk1 + s.z * wk2 + s.w * wk3;
                accV[g] += s.x * wv0 + s.y * wv1 + s.z * wv2 + s.w * wv3;
            }
        }
        #pragma unroll
        for (int g = 0; g < NG; ++g) { conk[g][tid] = accK[g]; vmat[g][tid] = accV[g]; }
    }
    __syncthreads();   // all samp reads done before bufA re-used as tmpk

    // ---- stage 6b: merged pos-q layer1 + pos-k layer1 (9 accumulators) ----
    {
        float acc[NG + 1];
        float biask = pk_b1[tid];
        #pragma unroll
        for (int g = 0; g < NG; ++g) acc[g] = biask;
        acc[NG] = pq_b1[tid];
        #pragma unroll 2
        for (int i = 0; i < D; i += 4) {
            float k0 = pk_W1[(i + 0) * D + tid], k1 = pk_W1[(i + 1) * D + tid];
            float k2 = pk_W1[(i + 2) * D + tid], k3 = pk_W1[(i + 3) * D + tid];
            float q0 = pq_W1[(i + 0) * D + tid], q1 = pq_W1[(i + 1) * D + tid];
            float q2 = pq_W1[(i + 2) * D + tid], q3 = pq_W1[(i + 3) * D + tid];
            #pragma unroll
            for (int g = 0; g < NG; ++g) {
                float4 s = *(const float4*)&bufB[g][i];   // kse
                acc[g] += s.x * k0 + s.y * k1 + s.z * k2 + s.w * k3;
            }
            float4 t = *(const float4*)&qse[i];
            acc[NG] += t.x * q0 + t.y * q1 + t.z * q2 + t.w * q3;
        }
        #pragma unroll
        for (int g = 0; g < NG; ++g) bufA[g][tid] = fmaxf(acc[g], 0.f);  // tmpk
        tmp1[tid] = fmaxf(acc[NG], 0.f);
    }
    __syncthreads();

    // ---- stage 7: merged pos-q layer2 (*query_scale) + pos-k layer2 ----
    {
        float acc[NG + 1];
        float biask = pk_b2[tid];
        #pragma unroll
        for (int g = 0; g < NG; ++g) acc[g] = biask;
        acc[NG] = pq_b2[tid];
        #pragma unroll 2
        for (int i = 0; i < D; i += 4) {
            float k0 = pk_W2[(i + 0) * D + tid], k1 = pk_W2[(i + 1) * D + tid];
            float k2 = pk_W2[(i + 2) * D + tid], k3 = pk_W2[(i + 3) * D + tid];
            float q0 = pq_W2[(i + 0) * D + tid], q1 = pq_W2[(i + 1) * D + tid];
            float q2 = pq_W2[(i + 2) * D + tid], q3 = pq_W2[(i + 3) * D + tid];
            #pragma unroll
            for (int g = 0; g < NG; ++g) {
                float4 s = *(const float4*)&bufA[g][i];   // tmpk
                acc[g] += s.x * k0 + s.y * k1 + s.z * k2 + s.w * k3;
            }
            float4 t = *(const float4*)&tmp1[i];
            acc[NG] += t.x * q0 + t.y * q1 + t.z * q2 + t.w * q3;
        }
        #pragma unroll
        for (int g = 0; g < NG; ++g) bufB[g][tid] = acc[g];           // posk
        posq[tid] = acc[NG] * query_scale[(size_t)q * D + tid];
    }
    __syncthreads();

    // ---- stage 8: sim[h][g] = (q . k) * SCALE (float4 reads) ----
    if (tid < NHD * NG) {
        int h = tid >> 3, g = tid & 7;
        float s = 0.f;
        #pragma unroll
        for (int d = 0; d < 32; d += 4) {
            float4 a = *(const float4*)&conq[h * 32 + d];
            float4 b = *(const float4*)&conk[g][h * 32 + d];
            float4 c = *(const float4*)&posq[h * 32 + d];
            float4 e = *(const float4*)&bufB[g][h * 32 + d];  // posk
            s += a.x * b.x + a.y * b.y + a.z * b.z + a.w * b.w;
            s += c.x * e.x + c.y * e.y + c.z * e.z + c.w * e.w;
        }
        sim[h][g] = s * 0.125f;   // SCALE = 64^-0.5
    }
    __syncthreads();

    // ---- stage 9: softmax over g ----
    if (tid < NHD) {
        int h = tid;
        float mx = sim[h][0];
        for (int g = 1; g < NG; ++g) mx = fmaxf(mx, sim[h][g]);
        float ex[NG], sum = 0.f;
        #pragma unroll
        for (int g = 0; g < NG; ++g) { ex[g] = expf(sim[h][g] - mx); sum += ex[g]; }
        float inv = 1.0f / sum;
        #pragma unroll
        for (int g = 0; g < NG; ++g) sim[h][g] = ex[g] * inv;
    }
    __syncthreads();

    // ---- stage 10: attention output (head-major, 8 heads x 32 dims) ----
    {
        int h = tid >> 5, d = tid & 31;
        float o = 0.f;
        #pragma unroll
        for (int g = 0; g < NG; ++g) o += sim[h][g] * vmat[g][h * 32 + d];
        oatt[tid] = o;
    }
    __syncthreads();

    // ---- stage 11: out = oatt @ out_W + out_b + dec_embed (float4 reads) ----
    {
        float acc = out_b[tid];
        #pragma unroll 4
        for (int i = 0; i < D; i += 4) {
            float4 o4 = *(const float4*)&oatt[i];
            acc += o4.x * out_W[(i + 0) * D + tid];
            acc += o4.y * out_W[(i + 1) * D + tid];
            acc += o4.z * out_W[(i + 2) * D + tid];
            acc += o4.w * out_W[(i + 3) * D + tid];
        }
        out[(size_t)q * D + tid] = acc + de[tid];
    }
}

extern "C" void kernel_launch(void* const* d_in, const int* in_sizes, int n_in,
                              void* d_out, int out_size, void* d_ws, size_t ws_size,
                              hipStream_t stream) {
    const float* dec_embed   = (const float*)d_in[0];
    const float* bev_feat    = (const float*)d_in[1];
    const float* query_scale = (const float*)d_in[2];
    const float* ref_points  = (const float*)d_in[3];
    const float* Wq     = (const float*)d_in[4];
    const float* bq     = (const float*)d_in[5];
    const float* Wk     = (const float*)d_in[6];
    const float* Wv     = (const float*)d_in[7];
    const float* pq_W1  = (const float*)d_in[8];
    const float* pq_b1  = (const float*)d_in[9];
    const float* pq_W2  = (const float*)d_in[10];
    const float* pq_b2  = (const float*)d_in[11];
    const float* pk_W1  = (const float*)d_in[12];
    const float* pk_b1  = (const float*)d_in[13];
    const float* pk_W2  = (const float*)d_in[14];
    const float* pk_b2  = (const float*)d_in[15];
    const float* off_W1 = (const float*)d_in[16];
    const float* off_b1 = (const float*)d_in[17];
    const float* off_W2 = (const float*)d_in[18];
    const float* off_b2 = (const float*)d_in[19];
    const float* out_W  = (const float*)d_in[20];
    const float* out_b  = (const float*)d_in[21];
    float* out = (float*)d_out;

    dca_kernel<<<NQ, 256, 0, stream>>>(dec_embed, bev_feat, query_scale, ref_points,
                                       Wq, bq, Wk, Wv,
                                       pq_W1, pq_b1, pq_W2, pq_b2,
                                       pk_W1, pk_b1, pk_W2, pk_b2,
                                       off_W1, off_b1, off_W2, off_b2,
                                       out_W, out_b, out);
}

// Round 3
// 731.267 us; speedup vs baseline: 1.0877x; 1.0081x over previous
//
#include <hip/hip_runtime.h>
#include <math.h>

#define NK 6
#define NB 8
#define NT 12
#define D 256      // DIM == HALF == 256
#define DP (D+4)   // padded LDS row (16B pad keeps float4 alignment, staggers banks)
#define NG 8       // offset groups == sampling points
#define NHD 8      // num heads
#define HW 256     // HBEV == WBEV
#define NQ (NK*NB*NT)   // 576 queries

// Algebraically-reduced monolithic kernel.
// Instead of materializing conk/posk/vmat (3 x 8-group 256x256 GEMVs = 1.6M MAC),
// contract weights with the query first:
//   sim_con[h][g] = samp_g . wqk[:,h],  wqk[i][h] = sum_d Wk[i][h*32+d]*conq[h*32+d]
//   sim_pos[h][g] = tmpk_g . wqpk[:,h], wqpk[j][h] = sum_d pk_W2[j][h*32+d]*posq[h*32+d]
//     (pk_b2 term is g-independent -> dropped, softmax shift-invariant)
//   oatt[c] = (sum_g attn[h(c)][g]*samp_g) . Wv[:,c]   (weight samples, then project)
// ~2.4M -> ~1.05M MAC/query; identical L2 weight traffic (each matrix read once/block).
__global__ __launch_bounds__(256)
void dca_kernel(const float* __restrict__ dec_embed,
                const float* __restrict__ bev_feat,
                const float* __restrict__ query_scale,
                const float* __restrict__ ref_points,
                const float* __restrict__ Wq,     const float* __restrict__ bq,
                const float* __restrict__ Wk,     const float* __restrict__ Wv,
                const float* __restrict__ pq_W1,  const float* __restrict__ pq_b1,
                const float* __restrict__ pq_W2,  const float* __restrict__ pq_b2,
                const float* __restrict__ pk_W1,  const float* __restrict__ pk_b1,
                const float* __restrict__ pk_W2,  const float* __restrict__ pk_b2,
                const float* __restrict__ off_W1, const float* __restrict__ off_b1,
                const float* __restrict__ off_W2, const float* __restrict__ off_b2,
                const float* __restrict__ out_W,  const float* __restrict__ out_b,
                float* __restrict__ out)
{
    __shared__ float de[D];
    __shared__ float conq[D];
    __shared__ float qse[D];
    __shared__ float tmp1[D];
    __shared__ float posq[D];
    __shared__ float oatt[D];
    __shared__ float h1[NG][64];
    __shared__ float gxy[NG][2];
    __shared__ float sim[NHD][NG];
    __shared__ float psum[64][4];
    __shared__ float samp[NG][DP];   // sampled bev rows      (st5 -> st11)
    __shared__ float kseW[NG][DP];   // kse (st5->st7), then wsamp (st11->st12)
    __shared__ float tmpk[NG][DP];   // relu(kse@pk_W1+b1)    (st7 -> st9)
    __shared__ float wqk [NHD][DP];  // Wk contracted with conq  (st5 -> st9)
    __shared__ float wqpk[NHD][DP];  // pk_W2 contracted w/ posq (st8 -> st9)

    const int tid = threadIdx.x;
    const int q   = blockIdx.x;              // flattened (k,b,t)
    const int bb  = (q / NT) % NB;           // batch index

    const float NORM = 0.01953125f;          // 2/102.4
    const float TWO_PI = 6.28318530717958647692f;
    const float L2_40_OVER_64 = 5.32192809488736234787f / 64.0f;  // log2(40)/64

    // ---- stage 1: load dec_embed row ----
    de[tid] = dec_embed[(size_t)q * D + tid];
    __syncthreads();

    // ---- stage 2: con_q = de @ Wq + bq ; qse sine embed (independent) ----
    {
        float acc = bq[tid];
        #pragma unroll 4
        for (int i = 0; i < D; i += 4) {
            float4 d4 = *(const float4*)&de[i];
            acc += d4.x * Wq[(i + 0) * D + tid];
            acc += d4.y * Wq[(i + 1) * D + tid];
            acc += d4.z * Wq[(i + 2) * D + tid];
            acc += d4.w * Wq[(i + 3) * D + tid];
        }
        conq[tid] = acc;
        float rx = ref_points[(size_t)q * 2 + 0] * NORM;
        float ry = ref_points[(size_t)q * 2 + 1] * NORM;
        float pos = (tid < 128) ? ry : rx;
        int m = (tid & 127) >> 1;
        float freq = TWO_PI / exp2f((float)m * L2_40_OVER_64);
        float e = pos * freq;
        qse[tid] = (tid & 1) ? cosf(e) : sinf(e);
    }
    __syncthreads();

    // ---- stage 3: offset MLP layer 1 (per group, 32 -> 64, exact GELU) ----
    for (int idx = tid; idx < NG * 64; idx += 256) {
        int g = idx >> 6, j = idx & 63;
        float acc = off_b1[j];
        #pragma unroll
        for (int i = 0; i < 32; i += 4) {
            float4 c4 = *(const float4*)&conq[g * 32 + i];
            acc += c4.x * off_W1[(i + 0) * 64 + j];
            acc += c4.y * off_W1[(i + 1) * 64 + j];
            acc += c4.z * off_W1[(i + 2) * 64 + j];
            acc += c4.w * off_W1[(i + 3) * 64 + j];
        }
        h1[g][j] = 0.5f * acc * (1.0f + erff(acc * 0.70710678118654752440f));
    }
    __syncthreads();

    // ---- stage 4: offset MLP layer 2 (64 -> 2), tanh*4, add ref, normalize ----
    if (tid < NG * 2) {
        int g = tid >> 1, c = tid & 1;
        float acc = off_b2[c];
        #pragma unroll
        for (int j = 0; j < 64; j += 4) {
            float4 hh = *(const float4*)&h1[g][j];
            acc += hh.x * off_W2[(j + 0) * 2 + c];
            acc += hh.y * off_W2[(j + 1) * 2 + c];
            acc += hh.z * off_W2[(j + 2) * 2 + c];
            acc += hh.w * off_W2[(j + 3) * 2 + c];
        }
        float off = tanhf(acc) * 4.0f;
        float rp  = ref_points[(size_t)q * 2 + c];
        gxy[g][c] = (rp + off) * NORM;
    }
    __syncthreads();

    // ---- stage 5: bilinear gather + kse sine embeds + wqk contraction ----
    {
        const float* ch = bev_feat + ((size_t)bb * D + tid) * HW * HW;
        #pragma unroll
        for (int g = 0; g < NG; ++g) {
            float gx = gxy[g][0], gy = gxy[g][1];
            float ix = ((gx + 1.0f) * HW - 1.0f) * 0.5f;
            float iy = ((gy + 1.0f) * HW - 1.0f) * 0.5f;
            float fx0 = floorf(ix), fy0 = floorf(iy);
            float wx = ix - fx0, wy = iy - fy0;
            int x0 = (int)fx0, y0 = (int)fy0;
            bool xin0 = (x0 >= 0) && (x0 < HW);
            bool xin1 = (x0 + 1 >= 0) && (x0 + 1 < HW);
            bool yin0 = (y0 >= 0) && (y0 < HW);
            bool yin1 = (y0 + 1 >= 0) && (y0 + 1 < HW);
            float v00 = 0.f, v01 = 0.f, v10 = 0.f, v11 = 0.f;
            if (yin0) {
                if (xin0) v00 = ch[y0 * HW + x0];
                if (xin1) v01 = ch[y0 * HW + x0 + 1];
            }
            if (yin1) {
                if (xin0) v10 = ch[(y0 + 1) * HW + x0];
                if (xin1) v11 = ch[(y0 + 1) * HW + x0 + 1];
            }
            samp[g][tid] = v00 * (1.f - wx) * (1.f - wy) + v01 * wx * (1.f - wy)
                         + v10 * (1.f - wx) * wy        + v11 * wx * wy;
        }
        // kse per group
        {
            int m = (tid & 127) >> 1;
            float freq = TWO_PI / exp2f((float)m * L2_40_OVER_64);
            #pragma unroll
            for (int g = 0; g < NG; ++g) {
                float pos = (tid < 128) ? gxy[g][1] : gxy[g][0];
                float e = pos * freq;
                kseW[g][tid] = (tid & 1) ? cosf(e) : sinf(e);
            }
        }
        // wqk[h][tid] = sum_d Wk[tid][h*32+d] * conq[h*32+d]  (row access, L1-tiled)
        {
            float acc[NHD] = {0.f,0.f,0.f,0.f,0.f,0.f,0.f,0.f};
            const float* wkrow = Wk + (size_t)tid * D;
            #pragma unroll
            for (int c = 0; c < D; c += 4) {
                float4 w  = *(const float4*)&wkrow[c];
                float4 cq = *(const float4*)&conq[c];
                acc[c >> 5] += w.x * cq.x + w.y * cq.y + w.z * cq.z + w.w * cq.w;
            }
            #pragma unroll
            for (int h = 0; h < NHD; ++h) wqk[h][tid] = acc[h];
        }
    }
    __syncthreads();

    // ---- stage 7: tmpk = relu(kse @ pk_W1 + b1), merged with pos-q layer1 ----
    {
        float acc[NG + 1];
        float biask = pk_b1[tid];
        #pragma unroll
        for (int g = 0; g < NG; ++g) acc[g] = biask;
        acc[NG] = pq_b1[tid];
        #pragma unroll 2
        for (int i = 0; i < D; i += 4) {
            float k0 = pk_W1[(i + 0) * D + tid], k1 = pk_W1[(i + 1) * D + tid];
            float k2 = pk_W1[(i + 2) * D + tid], k3 = pk_W1[(i + 3) * D + tid];
            float q0 = pq_W1[(i + 0) * D + tid], q1 = pq_W1[(i + 1) * D + tid];
            float q2 = pq_W1[(i + 2) * D + tid], q3 = pq_W1[(i + 3) * D + tid];
            #pragma unroll
            for (int g = 0; g < NG; ++g) {
                float4 s = *(const float4*)&kseW[g][i];
                acc[g] += s.x * k0 + s.y * k1 + s.z * k2 + s.w * k3;
            }
            float4 t = *(const float4*)&qse[i];
            acc[NG] += t.x * q0 + t.y * q1 + t.z * q2 + t.w * q3;
        }
        #pragma unroll
        for (int g = 0; g < NG; ++g) tmpk[g][tid] = fmaxf(acc[g], 0.f);
        tmp1[tid] = fmaxf(acc[NG], 0.f);
    }
    __syncthreads();

    // ---- stage 7.5: posq = (tmp1 @ pq_W2 + b2) * query_scale ----
    {
        float a2 = pq_b2[tid];
        #pragma unroll 4
        for (int i = 0; i < D; i += 4) {
            float4 t = *(const float4*)&tmp1[i];
            a2 += t.x * pq_W2[(i + 0) * D + tid];
            a2 += t.y * pq_W2[(i + 1) * D + tid];
            a2 += t.z * pq_W2[(i + 2) * D + tid];
            a2 += t.w * pq_W2[(i + 3) * D + tid];
        }
        posq[tid] = a2 * query_scale[(size_t)q * D + tid];
    }
    __syncthreads();

    // ---- stage 8: wqpk[h][tid] = sum_d pk_W2[tid][h*32+d] * posq[h*32+d] ----
    // (pk_b2 contribution to sim is g-independent -> softmax shift-invariant, dropped)
    {
        float acc[NHD] = {0.f,0.f,0.f,0.f,0.f,0.f,0.f,0.f};
        const float* wrow = pk_W2 + (size_t)tid * D;
        #pragma unroll
        for (int c = 0; c < D; c += 4) {
            float4 w  = *(const float4*)&wrow[c];
            float4 p4 = *(const float4*)&posq[c];
            acc[c >> 5] += w.x * p4.x + w.y * p4.y + w.z * p4.z + w.w * p4.w;
        }
        #pragma unroll
        for (int h = 0; h < NHD; ++h) wqpk[h][tid] = acc[h];
    }
    __syncthreads();

    // ---- stage 9: sim[h][g] = SCALE*(samp_g . wqk_h + tmpk_g . wqpk_h) ----
    // 4-way i-split across threads; padded rows keep residual conflicts <= 4-way.
    {
        int pair = tid >> 2, part = tid & 3;
        int h = pair >> 3, g = pair & 7;
        int i0 = part * 64;
        float s = 0.f;
        #pragma unroll
        for (int i = i0; i < i0 + 64; i += 4) {
            float4 a = *(const float4*)&samp[g][i];
            float4 b = *(const float4*)&wqk[h][i];
            float4 c = *(const float4*)&tmpk[g][i];
            float4 d = *(const float4*)&wqpk[h][i];
            s += a.x * b.x + a.y * b.y + a.z * b.z + a.w * b.w;
            s += c.x * d.x + c.y * d.y + c.z * d.z + c.w * d.w;
        }
        psum[pair][part] = s;
    }
    __syncthreads();
    if (tid < 64) {
        float s = psum[tid][0] + psum[tid][1] + psum[tid][2] + psum[tid][3];
        sim[tid >> 3][tid & 7] = s * 0.125f;   // SCALE = 64^-0.5
    }
    __syncthreads();

    // ---- stage 10: softmax over g ----
    if (tid < NHD) {
        int h = tid;
        float mx = sim[h][0];
        for (int g = 1; g < NG; ++g) mx = fmaxf(mx, sim[h][g]);
        float ex[NG], sum = 0.f;
        #pragma unroll
        for (int g = 0; g < NG; ++g) { ex[g] = expf(sim[h][g] - mx); sum += ex[g]; }
        float inv = 1.0f / sum;
        #pragma unroll
        for (int g = 0; g < NG; ++g) sim[h][g] = ex[g] * inv;
    }
    __syncthreads();

    // ---- stage 11: wsamp[h][i] = sum_g attn[h][g] * samp[g][i]  (into kseW) ----
    {
        float ws[NHD];
        #pragma unroll
        for (int h = 0; h < NHD; ++h) ws[h] = 0.f;
        #pragma unroll
        for (int g = 0; g < NG; ++g) {
            float sv = samp[g][tid];
            #pragma unroll
            for (int h = 0; h < NHD; ++h) ws[h] += sim[h][g] * sv;
        }
        #pragma unroll
        for (int h = 0; h < NHD; ++h) kseW[h][tid] = ws[h];
    }
    __syncthreads();

    // ---- stage 12: oatt[c] = wsamp[c>>5] . Wv[:,c] ----
    {
        int h = tid >> 5;
        float acc = 0.f;
        #pragma unroll 4
        for (int i = 0; i < D; i += 4) {
            float4 w4 = *(const float4*)&kseW[h][i];
            acc += w4.x * Wv[(i + 0) * D + tid];
            acc += w4.y * Wv[(i + 1) * D + tid];
            acc += w4.z * Wv[(i + 2) * D + tid];
            acc += w4.w * Wv[(i + 3) * D + tid];
        }
        oatt[tid] = acc;
    }
    __syncthreads();

    // ---- stage 13: out = oatt @ out_W + out_b + dec_embed ----
    {
        float acc = out_b[tid];
        #pragma unroll 4
        for (int i = 0; i < D; i += 4) {
            float4 o4 = *(const float4*)&oatt[i];
            acc += o4.x * out_W[(i + 0) * D + tid];
            acc += o4.y * out_W[(i + 1) * D + tid];
            acc += o4.z * out_W[(i + 2) * D + tid];
            acc += o4.w * out_W[(i + 3) * D + tid];
        }
        out[(size_t)q * D + tid] = acc + de[tid];
    }
}

extern "C" void kernel_launch(void* const* d_in, const int* in_sizes, int n_in,
                              void* d_out, int out_size, void* d_ws, size_t ws_size,
                              hipStream_t stream) {
    const float* dec_embed   = (const float*)d_in[0];
    const float* bev_feat    = (const float*)d_in[1];
    const float* query_scale = (const float*)d_in[2];
    const float* ref_points  = (const float*)d_in[3];
    const float* Wq     = (const float*)d_in[4];
    const float* bq     = (const float*)d_in[5];
    const float* Wk     = (const float*)d_in[6];
    const float* Wv     = (const float*)d_in[7];
    const float* pq_W1  = (const float*)d_in[8];
    const float* pq_b1  = (const float*)d_in[9];
    const float* pq_W2  = (const float*)d_in[10];
    const float* pq_b2  = (const float*)d_in[11];
    const float* pk_W1  = (const float*)d_in[12];
    const float* pk_b1  = (const float*)d_in[13];
    const float* pk_W2  = (const float*)d_in[14];
    const float* pk_b2  = (const float*)d_in[15];
    const float* off_W1 = (const float*)d_in[16];
    const float* off_b1 = (const float*)d_in[17];
    const float* off_W2 = (const float*)d_in[18];
    const float* off_b2 = (const float*)d_in[19];
    const float* out_W  = (const float*)d_in[20];
    const float* out_b  = (const float*)d_in[21];
    float* out = (float*)d_out;

    dca_kernel<<<NQ, 256, 0, stream>>>(dec_embed, bev_feat, query_scale, ref_points,
                                       Wq, bq, Wk, Wv,
                                       pq_W1, pq_b1, pq_W2, pq_b2,
                                       pk_W1, pk_b1, pk_W2, pk_b2,
                                       off_W1, off_b1, off_W2, off_b2,
                                       out_W, out_b, out);
}

// Round 4
// 722.455 us; speedup vs baseline: 1.1010x; 1.0122x over previous
//
#include <hip/hip_runtime.h>
#include <math.h>

#define NK 6
#define NB 8
#define NT 12
#define D 256      // DIM == HALF == 256
#define DP (D+4)   // padded LDS row (16B pad keeps float4 alignment, staggers banks)
#define NG 8       // offset groups == sampling points
#define NHD 8      // num heads
#define HW 256     // HBEV == WBEV
#define NQ (NK*NB*NT)   // 576 queries

// Algebraically-reduced monolithic kernel (R3) + gather-latency hiding (R4):
// all 32 bilinear corner loads are issued into registers FIRST (predicated,
// no LDS store between them), the independent kse/wqk compute runs while the
// scattered HBM loads are in flight, then the bilinear combine + LDS store.
__global__ __launch_bounds__(256)
void dca_kernel(const float* __restrict__ dec_embed,
                const float* __restrict__ bev_feat,
                const float* __restrict__ query_scale,
                const float* __restrict__ ref_points,
                const float* __restrict__ Wq,     const float* __restrict__ bq,
                const float* __restrict__ Wk,     const float* __restrict__ Wv,
                const float* __restrict__ pq_W1,  const float* __restrict__ pq_b1,
                const float* __restrict__ pq_W2,  const float* __restrict__ pq_b2,
                const float* __restrict__ pk_W1,  const float* __restrict__ pk_b1,
                const float* __restrict__ pk_W2,  const float* __restrict__ pk_b2,
                const float* __restrict__ off_W1, const float* __restrict__ off_b1,
                const float* __restrict__ off_W2, const float* __restrict__ off_b2,
                const float* __restrict__ out_W,  const float* __restrict__ out_b,
                float* __restrict__ out)
{
    __shared__ float de[D];
    __shared__ float conq[D];
    __shared__ float qse[D];
    __shared__ float tmp1[D];
    __shared__ float posq[D];
    __shared__ float oatt[D];
    __shared__ float h1[NG][64];
    __shared__ float gxy[NG][2];
    __shared__ float sim[NHD][NG];
    __shared__ float psum[64][4];
    __shared__ float samp[NG][DP];   // sampled bev rows      (st5 -> st11)
    __shared__ float kseW[NG][DP];   // kse (st5->st7), then wsamp (st11->st12)
    __shared__ float tmpk[NG][DP];   // relu(kse@pk_W1+b1)    (st7 -> st9)
    __shared__ float wqk [NHD][DP];  // Wk contracted with conq  (st5 -> st9)
    __shared__ float wqpk[NHD][DP];  // pk_W2 contracted w/ posq (st8 -> st9)

    const int tid = threadIdx.x;
    const int q   = blockIdx.x;              // flattened (k,b,t)
    const int bb  = (q / NT) % NB;           // batch index

    const float NORM = 0.01953125f;          // 2/102.4
    const float TWO_PI = 6.28318530717958647692f;
    const float L2_40_OVER_64 = 5.32192809488736234787f / 64.0f;  // log2(40)/64

    // ---- stage 1: load dec_embed row ----
    de[tid] = dec_embed[(size_t)q * D + tid];
    __syncthreads();

    // ---- stage 2: con_q = de @ Wq + bq ; qse sine embed (independent) ----
    {
        float acc = bq[tid];
        #pragma unroll 4
        for (int i = 0; i < D; i += 4) {
            float4 d4 = *(const float4*)&de[i];
            acc += d4.x * Wq[(i + 0) * D + tid];
            acc += d4.y * Wq[(i + 1) * D + tid];
            acc += d4.z * Wq[(i + 2) * D + tid];
            acc += d4.w * Wq[(i + 3) * D + tid];
        }
        conq[tid] = acc;
        float rx = ref_points[(size_t)q * 2 + 0] * NORM;
        float ry = ref_points[(size_t)q * 2 + 1] * NORM;
        float pos = (tid < 128) ? ry : rx;
        int m = (tid & 127) >> 1;
        float freq = TWO_PI / exp2f((float)m * L2_40_OVER_64);
        float e = pos * freq;
        qse[tid] = (tid & 1) ? __cosf(e) : __sinf(e);
    }
    __syncthreads();

    // ---- stage 3: offset MLP layer 1 (per group, 32 -> 64, exact GELU) ----
    for (int idx = tid; idx < NG * 64; idx += 256) {
        int g = idx >> 6, j = idx & 63;
        float acc = off_b1[j];
        #pragma unroll
        for (int i = 0; i < 32; i += 4) {
            float4 c4 = *(const float4*)&conq[g * 32 + i];
            acc += c4.x * off_W1[(i + 0) * 64 + j];
            acc += c4.y * off_W1[(i + 1) * 64 + j];
            acc += c4.z * off_W1[(i + 2) * 64 + j];
            acc += c4.w * off_W1[(i + 3) * 64 + j];
        }
        h1[g][j] = 0.5f * acc * (1.0f + erff(acc * 0.70710678118654752440f));
    }
    __syncthreads();

    // ---- stage 4: offset MLP layer 2 (64 -> 2), tanh*4, add ref, normalize ----
    if (tid < NG * 2) {
        int g = tid >> 1, c = tid & 1;
        float acc = off_b2[c];
        #pragma unroll
        for (int j = 0; j < 64; j += 4) {
            float4 hh = *(const float4*)&h1[g][j];
            acc += hh.x * off_W2[(j + 0) * 2 + c];
            acc += hh.y * off_W2[(j + 1) * 2 + c];
            acc += hh.z * off_W2[(j + 2) * 2 + c];
            acc += hh.w * off_W2[(j + 3) * 2 + c];
        }
        float off = tanhf(acc) * 4.0f;
        float rp  = ref_points[(size_t)q * 2 + c];
        gxy[g][c] = (rp + off) * NORM;
    }
    __syncthreads();

    // ---- stage 5: gather loads issued first, kse/wqk hide the latency ----
    {
        const float* ch = bev_feat + ((size_t)bb * D + tid) * HW * HW;
        float v00[NG], v01[NG], v10[NG], v11[NG], wxA[NG], wyA[NG];
        // (a) issue all 32 scattered loads (predicated selects, no stores between)
        #pragma unroll
        for (int g = 0; g < NG; ++g) {
            float gx = gxy[g][0], gy = gxy[g][1];
            float ix = ((gx + 1.0f) * HW - 1.0f) * 0.5f;
            float iy = ((gy + 1.0f) * HW - 1.0f) * 0.5f;
            float fx0 = floorf(ix), fy0 = floorf(iy);
            wxA[g] = ix - fx0; wyA[g] = iy - fy0;
            int x0 = (int)fx0, y0 = (int)fy0;
            bool xin0 = (x0 >= 0) && (x0 < HW);
            bool xin1 = (x0 + 1 >= 0) && (x0 + 1 < HW);
            bool yin0 = (y0 >= 0) && (y0 < HW);
            bool yin1 = (y0 + 1 >= 0) && (y0 + 1 < HW);
            v00[g] = (yin0 && xin0) ? ch[y0 * HW + x0]           : 0.f;
            v01[g] = (yin0 && xin1) ? ch[y0 * HW + x0 + 1]       : 0.f;
            v10[g] = (yin1 && xin0) ? ch[(y0 + 1) * HW + x0]     : 0.f;
            v11[g] = (yin1 && xin1) ? ch[(y0 + 1) * HW + x0 + 1] : 0.f;
        }
        // (b) kse per group (pure VALU, overlaps the in-flight gathers)
        {
            int m = (tid & 127) >> 1;
            float freq = TWO_PI / exp2f((float)m * L2_40_OVER_64);
            #pragma unroll
            for (int g = 0; g < NG; ++g) {
                float pos = (tid < 128) ? gxy[g][1] : gxy[g][0];
                float e = pos * freq;
                kseW[g][tid] = (tid & 1) ? __cosf(e) : __sinf(e);
            }
        }
        // (c) wqk[h][tid] = sum_d Wk[tid][h*32+d] * conq[h*32+d]  (row access)
        {
            float acc[NHD] = {0.f,0.f,0.f,0.f,0.f,0.f,0.f,0.f};
            const float* wkrow = Wk + (size_t)tid * D;
            #pragma unroll
            for (int c = 0; c < D; c += 4) {
                float4 w  = *(const float4*)&wkrow[c];
                float4 cq = *(const float4*)&conq[c];
                acc[c >> 5] += w.x * cq.x + w.y * cq.y + w.z * cq.z + w.w * cq.w;
            }
            #pragma unroll
            for (int h = 0; h < NHD; ++h) wqk[h][tid] = acc[h];
        }
        // (d) bilinear combine + LDS store (single wait point for all gathers)
        #pragma unroll
        for (int g = 0; g < NG; ++g) {
            float wx = wxA[g], wy = wyA[g];
            samp[g][tid] = v00[g] * (1.f - wx) * (1.f - wy) + v01[g] * wx * (1.f - wy)
                         + v10[g] * (1.f - wx) * wy         + v11[g] * wx * wy;
        }
    }
    __syncthreads();

    // ---- stage 7: tmpk = relu(kse @ pk_W1 + b1), merged with pos-q layer1 ----
    {
        float acc[NG + 1];
        float biask = pk_b1[tid];
        #pragma unroll
        for (int g = 0; g < NG; ++g) acc[g] = biask;
        acc[NG] = pq_b1[tid];
        #pragma unroll 2
        for (int i = 0; i < D; i += 4) {
            float k0 = pk_W1[(i + 0) * D + tid], k1 = pk_W1[(i + 1) * D + tid];
            float k2 = pk_W1[(i + 2) * D + tid], k3 = pk_W1[(i + 3) * D + tid];
            float q0 = pq_W1[(i + 0) * D + tid], q1 = pq_W1[(i + 1) * D + tid];
            float q2 = pq_W1[(i + 2) * D + tid], q3 = pq_W1[(i + 3) * D + tid];
            #pragma unroll
            for (int g = 0; g < NG; ++g) {
                float4 s = *(const float4*)&kseW[g][i];
                acc[g] += s.x * k0 + s.y * k1 + s.z * k2 + s.w * k3;
            }
            float4 t = *(const float4*)&qse[i];
            acc[NG] += t.x * q0 + t.y * q1 + t.z * q2 + t.w * q3;
        }
        #pragma unroll
        for (int g = 0; g < NG; ++g) tmpk[g][tid] = fmaxf(acc[g], 0.f);
        tmp1[tid] = fmaxf(acc[NG], 0.f);
    }
    __syncthreads();

    // ---- stage 7.5: posq = (tmp1 @ pq_W2 + b2) * query_scale ----
    {
        float a2 = pq_b2[tid];
        #pragma unroll 4
        for (int i = 0; i < D; i += 4) {
            float4 t = *(const float4*)&tmp1[i];
            a2 += t.x * pq_W2[(i + 0) * D + tid];
            a2 += t.y * pq_W2[(i + 1) * D + tid];
            a2 += t.z * pq_W2[(i + 2) * D + tid];
            a2 += t.w * pq_W2[(i + 3) * D + tid];
        }
        posq[tid] = a2 * query_scale[(size_t)q * D + tid];
    }
    __syncthreads();

    // ---- stage 8: wqpk[h][tid] = sum_d pk_W2[tid][h*32+d] * posq[h*32+d] ----
    // (pk_b2 contribution to sim is g-independent -> softmax shift-invariant)
    {
        float acc[NHD] = {0.f,0.f,0.f,0.f,0.f,0.f,0.f,0.f};
        const float* wrow = pk_W2 + (size_t)tid * D;
        #pragma unroll
        for (int c = 0; c < D; c += 4) {
            float4 w  = *(const float4*)&wrow[c];
            float4 p4 = *(const float4*)&posq[c];
            acc[c >> 5] += w.x * p4.x + w.y * p4.y + w.z * p4.z + w.w * p4.w;
        }
        #pragma unroll
        for (int h = 0; h < NHD; ++h) wqpk[h][tid] = acc[h];
    }
    __syncthreads();

    // ---- stage 9: sim[h][g] = SCALE*(samp_g . wqk_h + tmpk_g . wqpk_h) ----
    {
        int pair = tid >> 2, part = tid & 3;
        int h = pair >> 3, g = pair & 7;
        int i0 = part * 64;
        float s = 0.f;
        #pragma unroll
        for (int i = i0; i < i0 + 64; i += 4) {
            float4 a = *(const float4*)&samp[g][i];
            float4 b = *(const float4*)&wqk[h][i];
            float4 c = *(const float4*)&tmpk[g][i];
            float4 d = *(const float4*)&wqpk[h][i];
            s += a.x * b.x + a.y * b.y + a.z * b.z + a.w * b.w;
            s += c.x * d.x + c.y * d.y + c.z * d.z + c.w * d.w;
        }
        psum[pair][part] = s;
    }
    __syncthreads();
    if (tid < 64) {
        float s = psum[tid][0] + psum[tid][1] + psum[tid][2] + psum[tid][3];
        sim[tid >> 3][tid & 7] = s * 0.125f;   // SCALE = 64^-0.5
    }
    __syncthreads();

    // ---- stage 10: softmax over g ----
    if (tid < NHD) {
        int h = tid;
        float mx = sim[h][0];
        for (int g = 1; g < NG; ++g) mx = fmaxf(mx, sim[h][g]);
        float ex[NG], sum = 0.f;
        #pragma unroll
        for (int g = 0; g < NG; ++g) { ex[g] = __expf(sim[h][g] - mx); sum += ex[g]; }
        float inv = 1.0f / sum;
        #pragma unroll
        for (int g = 0; g < NG; ++g) sim[h][g] = ex[g] * inv;
    }
    __syncthreads();

    // ---- stage 11: wsamp[h][i] = sum_g attn[h][g] * samp[g][i]  (into kseW) ----
    {
        float wsm[NHD];
        #pragma unroll
        for (int h = 0; h < NHD; ++h) wsm[h] = 0.f;
        #pragma unroll
        for (int g = 0; g < NG; ++g) {
            float sv = samp[g][tid];
            #pragma unroll
            for (int h = 0; h < NHD; ++h) wsm[h] += sim[h][g] * sv;
        }
        #pragma unroll
        for (int h = 0; h < NHD; ++h) kseW[h][tid] = wsm[h];
    }
    __syncthreads();

    // ---- stage 12: oatt[c] = wsamp[c>>5] . Wv[:,c] ----
    {
        int h = tid >> 5;
        float acc = 0.f;
        #pragma unroll 4
        for (int i = 0; i < D; i += 4) {
            float4 w4 = *(const float4*)&kseW[h][i];
            acc += w4.x * Wv[(i + 0) * D + tid];
            acc += w4.y * Wv[(i + 1) * D + tid];
            acc += w4.z * Wv[(i + 2) * D + tid];
            acc += w4.w * Wv[(i + 3) * D + tid];
        }
        oatt[tid] = acc;
    }
    __syncthreads();

    // ---- stage 13: out = oatt @ out_W + out_b + dec_embed ----
    {
        float acc = out_b[tid];
        #pragma unroll 4
        for (int i = 0; i < D; i += 4) {
            float4 o4 = *(const float4*)&oatt[i];
            acc += o4.x * out_W[(i + 0) * D + tid];
            acc += o4.y * out_W[(i + 1) * D + tid];
            acc += o4.z * out_W[(i + 2) * D + tid];
            acc += o4.w * out_W[(i + 3) * D + tid];
        }
        out[(size_t)q * D + tid] = acc + de[tid];
    }
}

extern "C" void kernel_launch(void* const* d_in, const int* in_sizes, int n_in,
                              void* d_out, int out_size, void* d_ws, size_t ws_size,
                              hipStream_t stream) {
    const float* dec_embed   = (const float*)d_in[0];
    const float* bev_feat    = (const float*)d_in[1];
    const float* query_scale = (const float*)d_in[2];
    const float* ref_points  = (const float*)d_in[3];
    const float* Wq     = (const float*)d_in[4];
    const float* bq     = (const float*)d_in[5];
    const float* Wk     = (const float*)d_in[6];
    const float* Wv     = (const float*)d_in[7];
    const float* pq_W1  = (const float*)d_in[8];
    const float* pq_b1  = (const float*)d_in[9];
    const float* pq_W2  = (const float*)d_in[10];
    const float* pq_b2  = (const float*)d_in[11];
    const float* pk_W1  = (const float*)d_in[12];
    const float* pk_b1  = (const float*)d_in[13];
    const float* pk_W2  = (const float*)d_in[14];
    const float* pk_b2  = (const float*)d_in[15];
    const float* off_W1 = (const float*)d_in[16];
    const float* off_b1 = (const float*)d_in[17];
    const float* off_W2 = (const float*)d_in[18];
    const float* off_b2 = (const float*)d_in[19];
    const float* out_W  = (const float*)d_in[20];
    const float* out_b  = (const float*)d_in[21];
    float* out = (float*)d_out;

    dca_kernel<<<NQ, 256, 0, stream>>>(dec_embed, bev_feat, query_scale, ref_points,
                                       Wq, bq, Wk, Wv,
                                       pq_W1, pq_b1, pq_W2, pq_b2,
                                       pk_W1, pk_b1, pk_W2, pk_b2,
                                       off_W1, off_b1, off_W2, off_b2,
                                       out_W, out_b, out);
}